// Round 4
// baseline (226.952 us; speedup 1.0000x reference)
//
#include <hip/hip_runtime.h>
#include <hip/hip_bf16.h>

// SelfBiLayer B=256,L=2048,E=64,DA=64,R=32 -- MFMA round 4.
// Key insights vs round 3:
//  * mask is BINARY -> drop x*mask entirely; apply mask only in a=exp(Q)*m.
//    (masked tokens: a==0 exactly -> zero contribution to numerator+denominator)
//  * GEMM1 B-frags (lane=token, k=e contiguous) build directly from global x.
//  * GEMM2 computes Q (not Q^T): A=H token-major (LDS), B=W2^T from W2 rows.
//    C-frag then holds 4 CONSECUTIVE TOKENS per lane -> asT written as b64
//    pairs, ssum partials computed from the same bf16 registers.
//  * xT staging: token-quad threads -> 8 conflict-free b64 writes.
// Per block: (b, 256-token chunk), 2 sub-chunks of 128 tokens, 4 waves.

#define B_  256
#define L_  2048
#define E_  64
#define DA_ 64
#define R_  32
#define CH_ 8
#define NS_ 2

typedef __attribute__((ext_vector_type(8))) short bf16x8;
typedef __attribute__((ext_vector_type(4))) float f32x4;

// LDS word-offsets / pitches (words = 4B). All row bases 16B-aligned.
#define HS_P 36                 // hs row pitch (64 bf16 + pad)
#define XT_P 68                 // xT row pitch (128 bf16 + pad)
#define AS_P 68                 // asT row pitch
#define HS_W (128 * HS_P)       // 4608
#define XT_W (64 * XT_P)        // 4352
#define AS_W (32 * AS_P)        // 2176
#define SS_W (32 * 16)          // 512
// total = 11648 words = 46592 B -> 3 blocks/CU

__device__ __forceinline__ unsigned pk(float a, float b) {
    __hip_bfloat162 h = __float22bfloat162_rn(float2{a, b});   // v_cvt_pk_bf16_f32
    union { __hip_bfloat162 h2; unsigned u; } cv; cv.h2 = h;
    return cv.u;
}
__device__ __forceinline__ float bflo(unsigned u) { return __uint_as_float(u << 16); }
__device__ __forceinline__ float bfhi(unsigned u) { return __uint_as_float(u & 0xFFFF0000u); }
__device__ __forceinline__ float fast_tanh(float v) {
    // 1 - 2/(1+2^(v*2*log2e)) : mul, exp2, add, rcp, fma
    float e = __builtin_amdgcn_exp2f(v * 2.885390082f);
    float r = __builtin_amdgcn_rcpf(e + 1.0f);
    return fmaf(-2.0f, r, 1.0f);
}
__device__ __forceinline__ float fast_exp(float v) {
    return __builtin_amdgcn_exp2f(v * 1.442695041f);
}

__launch_bounds__(256, 3)
__global__ void selfbi_main(const float* __restrict__ x,
                            const float* __restrict__ mask,
                            const float* __restrict__ W1,
                            const float* __restrict__ W2,
                            float* __restrict__ accp,
                            float* __restrict__ ssump) {
    __shared__ __align__(16) unsigned smem[HS_W + XT_W + AS_W + SS_W];
    unsigned* hsw = smem;                    // H token-major bf16 (wave-private rows)
    unsigned* xtw = smem + HS_W;             // x e-major bf16 (transposed)
    unsigned* asw = xtw + XT_W;              // asT[r][t] bf16
    float*    ssp = (float*)(asw + AS_W);    // ssum partials [r][16]

    const int b    = blockIdx.x;
    const int c    = blockIdx.y;
    const int tid  = threadIdx.x;
    const int w    = tid >> 6;
    const int lane = tid & 63;
    const int g    = lane >> 4;     // k-octet group
    const int ml   = lane & 15;     // m/n lane
    const int p4   = tid & 31;      // xT staging: token-quad
    const int q8   = tid >> 5;      // xT staging: e-octet

    // ---- W1 A-frags + W2^T B-frags in registers (once per block) ----
    bf16x8 w1f[4][2], w2f[2][2];
    #pragma unroll
    for (int mt = 0; mt < 4; ++mt)
        #pragma unroll
        for (int kb = 0; kb < 2; ++kb) {
            const float* p = W1 + (16 * mt + ml) * E_ + 32 * kb + 8 * g;
            float4 a = *(const float4*)p, bb = *(const float4*)(p + 4);
            union { bf16x8 s; unsigned u[4]; } cv;
            cv.u[0] = pk(a.x, a.y); cv.u[1] = pk(a.z, a.w);
            cv.u[2] = pk(bb.x, bb.y); cv.u[3] = pk(bb.z, bb.w);
            w1f[mt][kb] = cv.s;
        }
    #pragma unroll
    for (int nt = 0; nt < 2; ++nt)
        #pragma unroll
        for (int kb = 0; kb < 2; ++kb) {
            const float* p = W2 + (16 * nt + ml) * DA_ + 32 * kb + 8 * g;
            float4 a = *(const float4*)p, bb = *(const float4*)(p + 4);
            union { bf16x8 s; unsigned u[4]; } cv;
            cv.u[0] = pk(a.x, a.y); cv.u[1] = pk(a.z, a.w);
            cv.u[2] = pk(bb.x, bb.y); cv.u[3] = pk(bb.z, bb.w);
            w2f[nt][kb] = cv.s;
        }

    f32x4 c3[2] = {f32x4{0,0,0,0}, f32x4{0,0,0,0}};
    float ssum_acc = 0.0f;

    for (int s = 0; s < NS_; ++s) {
        if (s) __syncthreads();    // xT/asT/ssp rewrite vs prev GEMM3/ssum readers

        const int    l0    = c * (NS_ * 128) + s * 128;
        const size_t xbase = ((size_t)b * L_ + l0) * E_;

        // ======== issue all global loads for this sub-chunk ========
        float xe[4][8];                       // xT staging: tokens 4p4..+3, e in [8q8,+8)
        #pragma unroll
        for (int k = 0; k < 4; ++k) {
            const float* p = x + xbase + (size_t)(4 * p4 + k) * E_ + 8 * q8;
            float4 a = *(const float4*)p, bb = *(const float4*)(p + 4);
            xe[k][0] = a.x;  xe[k][1] = a.y;  xe[k][2] = a.z;  xe[k][3] = a.w;
            xe[k][4] = bb.x; xe[k][5] = bb.y; xe[k][6] = bb.z; xe[k][7] = bb.w;
        }
        float4 gb[2][2][2];                   // GEMM1 B: token 32w+16nt+ml, e 32kb+8g..
        #pragma unroll
        for (int nt = 0; nt < 2; ++nt)
            #pragma unroll
            for (int kb = 0; kb < 2; ++kb) {
                const float* p = x + xbase + (size_t)(32 * w + 16 * nt + ml) * E_
                                 + 32 * kb + 8 * g;
                gb[nt][kb][0] = *(const float4*)p;
                gb[nt][kb][1] = *(const float4*)(p + 4);
            }
        float4 mk[2];                         // mask for tokens 32w+16mt+4g..+3
        #pragma unroll
        for (int mt = 0; mt < 2; ++mt)
            mk[mt] = *(const float4*)(mask + b * L_ + l0 + 32 * w + 16 * mt + 4 * g);

        // ======== xT: cross-token bf16 pairs, 8 b64 writes ========
        #pragma unroll
        for (int j = 0; j < 8; ++j) {
            uint2 u;
            u.x = pk(xe[0][j], xe[1][j]);
            u.y = pk(xe[2][j], xe[3][j]);
            *(uint2*)&xtw[(8 * q8 + j) * XT_P + 2 * p4] = u;
        }

        // ======== GEMM1: H^T[d][t], B-frags straight from registers ========
        bf16x8 xf[2][2];
        #pragma unroll
        for (int nt = 0; nt < 2; ++nt)
            #pragma unroll
            for (int kb = 0; kb < 2; ++kb) {
                union { bf16x8 s; unsigned u[4]; } cv;
                float4 a = gb[nt][kb][0], bb = gb[nt][kb][1];
                cv.u[0] = pk(a.x, a.y); cv.u[1] = pk(a.z, a.w);
                cv.u[2] = pk(bb.x, bb.y); cv.u[3] = pk(bb.z, bb.w);
                xf[nt][kb] = cv.s;
            }
        f32x4 c1[2][4];
        #pragma unroll
        for (int nt = 0; nt < 2; ++nt)
            #pragma unroll
            for (int mt = 0; mt < 4; ++mt) c1[nt][mt] = f32x4{0,0,0,0};
        #pragma unroll
        for (int kb = 0; kb < 2; ++kb)
            #pragma unroll
            for (int nt = 0; nt < 2; ++nt)
                #pragma unroll
                for (int mt = 0; mt < 4; ++mt)
                    c1[nt][mt] = __builtin_amdgcn_mfma_f32_16x16x32_bf16(
                        w1f[mt][kb], xf[nt][kb], c1[nt][mt], 0, 0, 0);

        // ======== tanh -> hs (token-major, wave-private rows) ========
        #pragma unroll
        for (int nt = 0; nt < 2; ++nt) {
            const int t = 32 * w + 16 * nt + ml;
            #pragma unroll
            for (int mt = 0; mt < 4; ++mt) {
                float h0 = fast_tanh(c1[nt][mt][0]);
                float h1 = fast_tanh(c1[nt][mt][1]);
                float h2 = fast_tanh(c1[nt][mt][2]);
                float h3 = fast_tanh(c1[nt][mt][3]);
                uint2 u; u.x = pk(h0, h1); u.y = pk(h2, h3);
                *(uint2*)&hsw[t * HS_P + 8 * mt + 2 * g] = u;   // d0=16mt+4g
            }
        }

        // ======== GEMM2': Q[t][r] = H @ W2^T (A=hs rows, wave-local) ========
        f32x4 c2[2][2];
        #pragma unroll
        for (int mt = 0; mt < 2; ++mt)
            #pragma unroll
            for (int nt = 0; nt < 2; ++nt) c2[mt][nt] = f32x4{0,0,0,0};
        #pragma unroll
        for (int kb = 0; kb < 2; ++kb)
            #pragma unroll
            for (int mt = 0; mt < 2; ++mt) {
                bf16x8 af = *(bf16x8*)&hsw[(32 * w + 16 * mt + ml) * HS_P
                                           + 16 * kb + 4 * g];
                #pragma unroll
                for (int nt = 0; nt < 2; ++nt)
                    c2[mt][nt] = __builtin_amdgcn_mfma_f32_16x16x32_bf16(
                        af, w2f[nt][kb], c2[mt][nt], 0, 0, 0);
            }

        // ======== exp*m -> asT (b64 pairs) + ssum partials ========
        float part[2] = {0.f, 0.f};
        #pragma unroll
        for (int mt = 0; mt < 2; ++mt) {
            const float m0 = mk[mt].x, m1 = mk[mt].y, m2 = mk[mt].z, m3 = mk[mt].w;
            const int tw = 16 * w + 8 * mt + 2 * g;    // t0/2, t0 = 32w+16mt+4g
            #pragma unroll
            for (int nt = 0; nt < 2; ++nt) {
                float a0 = fast_exp(c2[mt][nt][0]) * m0;
                float a1 = fast_exp(c2[mt][nt][1]) * m1;
                float a2 = fast_exp(c2[mt][nt][2]) * m2;
                float a3 = fast_exp(c2[mt][nt][3]) * m3;
                uint2 u; u.x = pk(a0, a1); u.y = pk(a2, a3);
                *(uint2*)&asw[(16 * nt + ml) * AS_P + tw] = u;
                part[nt] += bflo(u.x) + bfhi(u.x) + bflo(u.y) + bfhi(u.y);
            }
        }
        #pragma unroll
        for (int nt = 0; nt < 2; ++nt)
            ssp[(16 * nt + ml) * 16 + 4 * w + g] = part[nt];

        __syncthreads();   // asT + xT + ssp visible to all waves

        // ======== GEMM3: acc[r][e] += a^T @ x ========
        #pragma unroll
        for (int kb = 0; kb < 4; ++kb) {
            bf16x8 bf = *(bf16x8*)&xtw[(16 * w + ml) * XT_P + 16 * kb + 4 * g];
            #pragma unroll
            for (int mt = 0; mt < 2; ++mt) {
                bf16x8 af = *(bf16x8*)&asw[(16 * mt + ml) * AS_P + 16 * kb + 4 * g];
                c3[mt] = __builtin_amdgcn_mfma_f32_16x16x32_bf16(af, bf, c3[mt], 0, 0, 0);
            }
        }

        // ======== ssum: 32 threads reduce ssp for this sub-chunk ========
        if (tid < 32) {
            const float4* q = (const float4*)&ssp[tid * 16];
            float4 q0 = q[0], q1 = q[1], q2 = q[2], q3 = q[3];
            ssum_acc += (q0.x + q0.y + q0.z + q0.w) + (q1.x + q1.y + q1.z + q1.w)
                      + (q2.x + q2.y + q2.z + q2.w) + (q3.x + q3.y + q3.z + q3.w);
        }
    }

    // ======== epilogue: partial store ========
    const size_t obase = (size_t)(b * CH_ + c) * (R_ * E_);
    const int e = 16 * w + ml;
    #pragma unroll
    for (int mt = 0; mt < 2; ++mt)
        #pragma unroll
        for (int reg = 0; reg < 4; ++reg) {
            const int r = 16 * mt + 4 * g + reg;
            accp[obase + r * E_ + e] = c3[mt][reg];
        }
    if (tid < 32) ssump[(b * CH_ + c) * R_ + tid] = ssum_acc;
}

__launch_bounds__(256, 4)
__global__ void selfbi_reduce(const float* __restrict__ accp,
                              const float* __restrict__ ssump,
                              float* __restrict__ out) {
    const int of = blockIdx.x * 256 + threadIdx.x;  // flat (b,r,e)
    const int b  = of >> 11;
    const int o  = of & 2047;
    const int r  = o >> 6;
    float num = 0.f, den = 0.f;
    #pragma unroll
    for (int cc = 0; cc < CH_; ++cc) {
        num += accp[((size_t)(b * CH_ + cc)) * (R_ * E_) + o];
        den += ssump[(b * CH_ + cc) * R_ + r];
    }
    out[of] = num / den;
}

extern "C" void kernel_launch(void* const* d_in, const int* in_sizes, int n_in,
                              void* d_out, int out_size, void* d_ws, size_t ws_size,
                              hipStream_t stream) {
    const float* x    = (const float*)d_in[0];   // (B,L,E)
    const float* mask = (const float*)d_in[1];   // (B,L)
    const float* W1   = (const float*)d_in[2];   // (DA,E)
    const float* W2   = (const float*)d_in[3];   // (R,DA)
    float* out        = (float*)d_out;           // (B,R,E)

    float* accp  = (float*)d_ws;                        // B*CH*R*E fp32 = 16.8 MB
    float* ssump = accp + (size_t)B_ * CH_ * R_ * E_;   // B*CH*R fp32

    selfbi_main<<<dim3(B_, CH_), dim3(256), 0, stream>>>(x, mask, W1, W2, accp, ssump);
    selfbi_reduce<<<dim3((B_ * R_ * E_) / 256), dim3(256), 0, stream>>>(accp, ssump, out);
}